// Round 11
// baseline (198.868 us; speedup 1.0000x reference)
//
#include <hip/hip_runtime.h>

typedef short bf16x8 __attribute__((ext_vector_type(8)));
typedef float f32x4 __attribute__((ext_vector_type(4)));
typedef unsigned short u16x4 __attribute__((ext_vector_type(4)));

__device__ __forceinline__ unsigned short f2b(float f) {
    unsigned int u = __builtin_bit_cast(unsigned int, f);
    u += 0x7fffu + ((u >> 16) & 1u);   // RNE
    return (unsigned short)(u >> 16);
}
__device__ __forceinline__ float b2f(unsigned short s) {
    unsigned int u = ((unsigned int)s) << 16;
    return __builtin_bit_cast(float, u);
}

// wt[k][i][j] = bf16(w1[j][k][i]);  k<3, i<128, j<64
__global__ void wt_prepass(const float* __restrict__ w1, unsigned short* __restrict__ wt) {
    int t = blockIdx.x * 256 + threadIdx.x;
    if (t >= 24576) return;
    int j = t & 63;
    int i = (t >> 6) & 127;
    int k = t >> 13;
    wt[t] = f2b(w1[(j * 3 + k) * 128 + i]);
}

// xs: row = a*13 + s; byte = (row<<7) + ((j*2) ^ ((row&7)<<4))   [rows 0..363, 46592 B]
// t4s (overlays xs): [ic 0..63][cl][l] u16, byte = ic*512 + cl*64 + ((l*2) ^ (((ic*7+cl)&7)<<3))
//   l = a+1 mod 28 applied at WRITE time; XOR scoped to l-dim -> injective.  [32768 B]
// twin-block split: each block computes one i-half (ih). acc = 56 floats -> fits 3 blocks/CU.

__global__ __launch_bounds__(256, 3) void fused_main(
        const float* __restrict__ x, const float* __restrict__ w0,
        const unsigned short* __restrict__ wt, float* __restrict__ y) {
    __shared__ __align__(16) char smem[46592];   // xs, later t4s (32K)
    __shared__ float w0s[256];

    const int tid  = threadIdx.x;
    const int lane = tid & 63;
    const int w    = tid >> 6;
    const int rl   = lane & 15;
    const int jb0  = (lane >> 4) << 3;

    // dispatch-consecutive groups of 8 (bc 0..3 x ih 0..1) on one XCD share one b's x-window
    const int B     = (int)blockIdx.x;
    const int xcd   = B & 7;
    const int g     = B >> 3;            // 0..1023
    const int bc    = g & 3;
    const int ih    = (g >> 2) & 1;
    const int bslot = g >> 3;            // 0..127
    const int b     = (xcd << 7) + bslot;
    const int c0    = 7 * bc;

    w0s[tid] = w0[tid];

    // ---- zero-fill halo slots (bc0: s=0,11 ; bc3: s=9) ----
    {
        int nh = (bc == 0) ? 2 : ((bc == 3) ? 1 : 0);
        for (int idx = tid; idx < nh * 224; idx += 256) {
            int rr = idx;
            int sl;
            if (bc == 0) {
                if (rr >= 224) { sl = 11; rr -= 224; } else sl = 0;
            } else {
                sl = 9;                 // bc == 3
            }
            int a   = rr >> 3, ch = rr & 7;
            int row = a * 13 + sl;
            int byte = (row << 7) + ((ch << 4) ^ ((row & 7) << 4));
            *reinterpret_cast<f32x4*>(smem + byte) = f32x4{0.f, 0.f, 0.f, 0.f};
        }
    }

    // ---- staging: 3 batches of 7 independent float4 loads -> scatter ----
    int q0, q1, q2;
    if      (bc == 0) { q0 = 0; q1 = 1; q2 = 6; }
    else if (bc == 1) { q0 = 1; q1 = 2; q2 = 3; }
    else if (bc == 2) { q0 = 3; q1 = 4; q2 = 5; }
    else              { q0 = 4; q1 = 5; q2 = 6; }

    const float* xb = x + (size_t)b * (1792 * 28);
    for (int bt = 0; bt < 3; ++bt) {
        float4 vbuf[7];
#pragma unroll
        for (int u = 0; u < 7; ++u) {
            int f  = tid + (((bt * 7) + u) << 8);
            int R  = f / 3;
            int q3 = f - R * 3;
            int q  = (q3 == 0) ? q0 : ((q3 == 1) ? q1 : q2);
            vbuf[u] = *reinterpret_cast<const float4*>(xb + R * 28 + (q << 2));
        }
#pragma unroll
        for (int u = 0; u < 7; ++u) {
            int f  = tid + (((bt * 7) + u) << 8);
            int R  = f / 3;
            int q3 = f - R * 3;
            int q  = (q3 == 0) ? q0 : ((q3 == 1) ? q1 : q2);
            int a  = R % 28;
            int j2 = (R / 28) << 1;
            float vv[4] = {vbuf[u].x, vbuf[u].y, vbuf[u].z, vbuf[u].w};
#pragma unroll
            for (int e = 0; e < 4; ++e) {
                int n = (q << 2) + e;
                int sl; bool ok;
                if (bc == 0) {
                    if (n < 8)        { sl = n + 1;  ok = true; }
                    else if (n >= 26) { sl = n - 17; ok = true; }
                    else              { sl = 0;      ok = false; }
                } else {
                    sl = n + 2 - c0;
                    ok = (unsigned)sl < 10u;
                }
                if (ok) {
                    int row  = a * 13 + sl;
                    int byte = (row << 7) + (j2 ^ ((row & 7) << 4));
                    *(unsigned short*)(smem + byte) = f2b(vv[e]);
                }
            }
        }
    }
    __syncthreads();

    // ---- K-loop: per wave 14 m-tiles x 1 n-tile (16 i), 6 K-steps of 32 ----
    const int cl = rl & 7;
    const int rh = rl >> 3;
    int rowoff[3];
#pragma unroll
    for (int k = 0; k < 3; ++k) {
        int sIdx = (bc == 0) ? ((cl == 0) ? (9 + k) : (cl - 1 + k)) : (cl + k);
        rowoff[k] = rh * 13 + sIdx;
    }

    const int iglob = (ih << 6) + (w << 4) + rl;    // this thread's B-fragment column

    f32x4 acc[14];
#pragma unroll
    for (int mt = 0; mt < 14; ++mt) acc[mt] = f32x4{0.f, 0.f, 0.f, 0.f};

#pragma unroll
    for (int s = 0; s < 6; ++s) {
        const int k  = s >> 1;
        const int jb = ((s & 1) << 5) + jb0;
        const int jx = jb << 1;
        bf16x8 bf = *reinterpret_cast<const bf16x8*>(wt + (k << 13) + (iglob << 6) + jb);
#pragma unroll
        for (int mt = 0; mt < 14; ++mt) {
            int row  = 26 * mt + rowoff[k];
            int byte = (row << 7) + (jx ^ ((row & 7) << 4));
            bf16x8 af = *reinterpret_cast<const bf16x8*>(smem + byte);
            acc[mt] = __builtin_amdgcn_mfma_f32_16x16x32_bf16(af, bf, acc[mt], 0, 0, 0);
        }
    }
    __syncthreads();

    // ---- epilogue writes: t4s[ic][cl][l] (local ic 0..63), scalar b16 ----
    {
        const int rq  = (lane >> 4) << 2;
        const int icb = (w << 4) + rl;              // local ic
#pragma unroll
        for (int mt = 0; mt < 14; ++mt) {
            int rbase = (mt << 4) + rq;
            int a     = rbase >> 3;
            int l     = (a == 27) ? 0 : (a + 1);    // roll applied at write
            int l2    = l << 1;
            int clb   = rbase & 7;                  // 0 or 4
            int base  = (icb << 9);
            int ic7   = icb * 7;
#pragma unroll
            for (int q = 0; q < 4; ++q) {
                int cc   = clb + q;
                int byte = base + (cc << 6) + (l2 ^ (((ic7 + cc) & 7) << 3));
                *(unsigned short*)(smem + byte) = f2b(acc[mt][q]);
            }
        }
    }
    __syncthreads();

    // ---- combine with w0: 2 x ds_read_b64 per output float4; nt stores ----
    for (int f = tid; f < 3136; f += 256) {
        int lq    = f % 7;
        int t1    = f / 7;
        int m_loc = t1 % 7;
        int iloc  = t1 / 7;                     // local 0..63
        int ig    = (ih << 6) + iloc;
        float w00 = w0s[2 * ig], w01 = w0s[2 * ig + 1];
        int m     = c0 + m_loc;
        int lo    = lq << 3;
        int i7    = iloc * 7;
        int cl1   = m_loc + 1;                  // c = m
        int cl2   = m_loc;                      // c = m-1
        int by1   = (iloc << 9) + (cl1 << 6) + (lo ^ (((i7 + cl1) & 7) << 3));
        int by2   = (iloc << 9) + (cl2 << 6) + (lo ^ (((i7 + cl2) & 7) << 3));
        u16x4 h1  = *reinterpret_cast<const u16x4*>(smem + by1);
        u16x4 h2  = *reinterpret_cast<const u16x4*>(smem + by2);
        f32x4 o;
        o.x = w00 * b2f(h1.x) + w01 * b2f(h2.x);
        o.y = w00 * b2f(h1.y) + w01 * b2f(h2.y);
        o.z = w00 * b2f(h1.z) + w01 * b2f(h2.z);
        o.w = w00 * b2f(h1.w) + w01 * b2f(h2.w);
        __builtin_nontemporal_store(
            o, reinterpret_cast<f32x4*>(y + ((((size_t)b * 128 + ig) * 28 + m) * 28) + (lq << 2)));
    }
}

extern "C" void kernel_launch(void* const* d_in, const int* in_sizes, int n_in,
                              void* d_out, int out_size, void* d_ws, size_t ws_size,
                              hipStream_t stream) {
    const float* x  = (const float*)d_in[0];
    const float* w0 = (const float*)d_in[1];
    const float* w1 = (const float*)d_in[2];
    float* y = (float*)d_out;
    unsigned short* wt = (unsigned short*)d_ws;   // 24576 u16 = 48 KiB

    hipLaunchKernelGGL(wt_prepass, dim3(96), dim3(256), 0, stream, w1, wt);
    hipLaunchKernelGGL(fused_main, dim3(8192), dim3(256), 0, stream, x, w0, wt, y);
}